// Round 2
// baseline (756.460 us; speedup 1.0000x reference)
//
#include <hip/hip_runtime.h>
#include <hip/hip_bf16.h>
#include <math.h>

#define BB 128
#define NN 2048
#define FIN 17

typedef unsigned short ushort_t;
typedef __attribute__((ext_vector_type(8))) unsigned short u16x8;

__device__ __forceinline__ float b2f(unsigned short u) {
    unsigned int v = ((unsigned int)u) << 16;
    return __builtin_bit_cast(float, v);
}
__device__ __forceinline__ unsigned short f2b(float f) {
    __hip_bfloat16 h = __float2bfloat16(f);
    return __builtin_bit_cast(unsigned short, h);
}
__device__ __forceinline__ float gelu_f(float x) {
    return 0.5f * x * (1.0f + erff(x * 0.70710678118654752f));
}
__device__ __forceinline__ float lrelu_f(float x) {
    return x >= 0.0f ? x : 0.2f * x;
}

// ---------------- Stage 1: x = LN(gelu(in @ W_node + b_node)) -> [Bc*N,128] bf16
__global__ __launch_bounds__(256) void k_fcnode(
    const float* __restrict__ X, const float* __restrict__ W,
    const float* __restrict__ bias, const float* __restrict__ g,
    const float* __restrict__ beta, ushort_t* __restrict__ out) {
    __shared__ float Wl[FIN * 128];
    __shared__ float bl[128], gl[128], bet[128];
    __shared__ float xrow[8][20];
    for (int i = threadIdx.x; i < FIN * 128; i += 256) Wl[i] = W[i];
    if (threadIdx.x < 128) {
        bl[threadIdx.x] = bias[threadIdx.x];
        gl[threadIdx.x] = g[threadIdx.x];
        bet[threadIdx.x] = beta[threadIdx.x];
    }
    int grp = threadIdx.x >> 5, lane = threadIdx.x & 31;
    int row = blockIdx.x * 8 + grp;
    if (lane < FIN) xrow[grp][lane] = X[(long long)row * FIN + lane];
    __syncthreads();
    float acc[4] = {0.f, 0.f, 0.f, 0.f};
#pragma unroll
    for (int k = 0; k < FIN; k++) {
        float xv = xrow[grp][k];
#pragma unroll
        for (int j = 0; j < 4; j++) acc[j] = fmaf(xv, Wl[k * 128 + lane + 32 * j], acc[j]);
    }
    float v[4], s = 0.f, sq = 0.f;
#pragma unroll
    for (int j = 0; j < 4; j++) {
        v[j] = gelu_f(acc[j] + bl[lane + 32 * j]);
        s += v[j]; sq += v[j] * v[j];
    }
#pragma unroll
    for (int m = 16; m >= 1; m >>= 1) { s += __shfl_xor(s, m, 32); sq += __shfl_xor(sq, m, 32); }
    float mean = s * (1.f / 128.f);
    float var = sq * (1.f / 128.f) - mean * mean;
    float rstd = rsqrtf(var + 1e-5f);
#pragma unroll
    for (int j = 0; j < 4; j++) {
        int c = lane + 32 * j;
        out[(long long)row * 128 + c] = f2b((v[j] - mean) * rstd * gl[c] + bet[c]);
    }
}

// ---------------- xr0[b] = X[b,0,:] @ Wr + br  -> [Bc,96] f32
template <int K>
__global__ __launch_bounds__(128) void k_xr0(
    const ushort_t* __restrict__ X, const float* __restrict__ Wr,
    const float* __restrict__ br, float* __restrict__ xr0) {
    int b = blockIdx.x, c = threadIdx.x;
    __shared__ float xs[K];
    if (threadIdx.x < K) xs[threadIdx.x] = b2f(X[(long long)b * NN * K + threadIdx.x]);
    __syncthreads();
    if (c >= 96) return;
    float acc = br[c];
    for (int k = 0; k < K; k++) acc = fmaf(xs[k], Wr[k * 96 + c], acc);
    xr0[b * 96 + c] = acc;
}

// ---------------- conv GEMM: xl = X@Wl+bl; scores; finalize rows n>0
// Each block: 32 rows; 8 warpgroups of 32 lanes; lane owns channels 3l..3l+2.
template <int K>
__global__ __launch_bounds__(256) void k_conv(
    const ushort_t* __restrict__ X,  // [Bc*N,K] bf16
    const float* __restrict__ Wl,    // [K,96]
    const float* __restrict__ bl, const float* __restrict__ att,
    const float* __restrict__ xr0,   // [Bc,96]
    const float* __restrict__ bias, const float* __restrict__ lng,
    const float* __restrict__ lnb,
    ushort_t* __restrict__ XLraw,    // [Bc*N,96] bf16
    float* __restrict__ scores,      // [Bc*N,3]
    ushort_t* __restrict__ Xout)     // [Bc*N,96] bf16
{
    __shared__ float Ws[K * 96];
    int tid = threadIdx.x;
    for (int i = tid; i < K * 96; i += 256) Ws[i] = Wl[i];
    __syncthreads();
    int grp = tid >> 5, lane = tid & 31;
    int row0 = blockIdx.x * 32 + grp * 4;
    int b = (blockIdx.x * 32) >> 11;  // chunk-local batch (NN=2048)
    int c0 = 3 * lane;
    float acc[4][3];
#pragma unroll
    for (int r = 0; r < 4; r++)
#pragma unroll
        for (int j = 0; j < 3; j++) acc[r][j] = 0.f;
    const u16x8* Xp = (const u16x8*)(X + (long long)row0 * K);
    for (int k8 = 0; k8 < K / 8; ++k8) {
        u16x8 xv[4];
#pragma unroll
        for (int r = 0; r < 4; r++) xv[r] = Xp[r * (K / 8) + k8];
#pragma unroll
        for (int kk = 0; kk < 8; kk++) {
            int k = k8 * 8 + kk;
            float w0 = Ws[k * 96 + c0], w1 = Ws[k * 96 + c0 + 1], w2 = Ws[k * 96 + c0 + 2];
#pragma unroll
            for (int r = 0; r < 4; r++) {
                float x = b2f(xv[r][kk]);
                acc[r][0] = fmaf(x, w0, acc[r][0]);
                acc[r][1] = fmaf(x, w1, acc[r][1]);
                acc[r][2] = fmaf(x, w2, acc[r][2]);
            }
        }
    }
    float blc[3], xrc[3], attc[3], bic[3], gc[3], bc[3];
#pragma unroll
    for (int j = 0; j < 3; j++) {
        int c = c0 + j;
        blc[j] = bl[c]; xrc[j] = xr0[b * 96 + c]; attc[j] = att[c];
        bic[j] = bias[c]; gc[j] = lng[c]; bc[j] = lnb[c];
    }
#pragma unroll
    for (int r = 0; r < 4; r++) {
        int row = row0 + r;
        float xlv[3];
        float p0 = 0.f, p1 = 0.f, p2 = 0.f;
#pragma unroll
        for (int j = 0; j < 3; j++) {
            xlv[j] = acc[r][j] + blc[j];
            XLraw[(long long)row * 96 + c0 + j] = f2b(xlv[j]);
            float e = lrelu_f(xlv[j] + xrc[j]);
            float p = attc[j] * e;
            int h = (c0 + j) >> 5;
            if (h == 0) p0 += p; else if (h == 1) p1 += p; else p2 += p;
        }
#pragma unroll
        for (int mk = 16; mk >= 1; mk >>= 1) {
            p0 += __shfl_xor(p0, mk, 32);
            p1 += __shfl_xor(p1, mk, 32);
            p2 += __shfl_xor(p2, mk, 32);
        }
        if (lane == 0) {
            scores[(long long)row * 3 + 0] = p0;
            scores[(long long)row * 3 + 1] = p1;
            scores[(long long)row * 3 + 2] = p2;
        }
        float o[3], s = 0.f, sq = 0.f;
#pragma unroll
        for (int j = 0; j < 3; j++) {
            o[j] = gelu_f(xlv[j] + bic[j]);
            s += o[j]; sq += o[j] * o[j];
        }
#pragma unroll
        for (int mk = 16; mk >= 1; mk >>= 1) { s += __shfl_xor(s, mk, 32); sq += __shfl_xor(sq, mk, 32); }
        float mean = s * (1.f / 96.f);
        float var = sq * (1.f / 96.f) - mean * mean;
        float rstd = rsqrtf(var + 1e-5f);
        if ((row & (NN - 1)) != 0) {
#pragma unroll
            for (int j = 0; j < 3; j++)
                Xout[(long long)row * 96 + c0 + j] = f2b((o[j] - mean) * rstd * gc[j] + bc[j]);
        }
    }
}

// ---------------- per-(b,h): softmax over N scores, out0 = sum alpha*xl
__global__ __launch_bounds__(256) void k_agg(
    const float* __restrict__ scores, const ushort_t* __restrict__ XL,
    float* __restrict__ out0) {
    int b = blockIdx.x / 3, h = blockIdx.x - b * 3;
    __shared__ float als[NN];
    __shared__ float red[4];
    __shared__ float Zs;
    __shared__ float racc[8][33];
    int tid = threadIdx.x;
    const float* sb = scores + (long long)b * NN * 3 + h;
    float m = -1e30f;
    for (int n = tid; n < NN; n += 256) m = fmaxf(m, sb[n * 3]);
#pragma unroll
    for (int mk = 32; mk >= 1; mk >>= 1) m = fmaxf(m, __shfl_xor(m, mk, 64));
    if ((tid & 63) == 0) red[tid >> 6] = m;
    __syncthreads();
    m = fmaxf(fmaxf(red[0], red[1]), fmaxf(red[2], red[3]));
    __syncthreads();
    float s = 0.f;
    for (int n = tid; n < NN; n += 256) {
        float e = expf(sb[n * 3] - m);
        als[n] = e;
        s += e;
    }
#pragma unroll
    for (int mk = 32; mk >= 1; mk >>= 1) s += __shfl_xor(s, mk, 64);
    if ((tid & 63) == 0) red[tid >> 6] = s;
    __syncthreads();
    if (tid == 0) Zs = red[0] + red[1] + red[2] + red[3];
    int cl = tid & 31, ns = tid >> 5;
    float acc = 0.f;
    const ushort_t* xb = XL + (long long)b * NN * 96 + h * 32 + cl;
    for (int n = ns; n < NN; n += 8) acc += als[n] * b2f(xb[(long long)n * 96]);
    racc[ns][cl] = acc;
    __syncthreads();
    if (tid < 32) {
        float a = 0.f;
#pragma unroll
        for (int k = 0; k < 8; k++) a += racc[k][tid];
        out0[b * 96 + tid + h * 32] = a / Zs;
    }
}

// ---------------- finalize node-0 row: X2[b,0,:] = LN(gelu(out0 + bias))
__global__ __launch_bounds__(128) void k_row0(
    const float* __restrict__ out0, const float* __restrict__ bias,
    const float* __restrict__ g, const float* __restrict__ beta,
    ushort_t* __restrict__ X2) {
    int b = blockIdx.x, t = threadIdx.x;
    __shared__ float vv[96];
    __shared__ float red2[2];
    float val = 0.f;
    if (t < 96) {
        val = gelu_f(out0[b * 96 + t] + bias[t]);
        vv[t] = val;
    }
    __syncthreads();
    if (t < 32) {
        float a = vv[t], b2 = vv[t + 32], c = vv[t + 64];
        float s = a + b2 + c, sq = a * a + b2 * b2 + c * c;
#pragma unroll
        for (int mk = 16; mk >= 1; mk >>= 1) { s += __shfl_xor(s, mk, 32); sq += __shfl_xor(sq, mk, 32); }
        if (t == 0) { red2[0] = s; red2[1] = sq; }
    }
    __syncthreads();
    float mean = red2[0] * (1.f / 96.f);
    float var = red2[1] * (1.f / 96.f) - mean * mean;
    float rstd = rsqrtf(var + 1e-5f);
    if (t < 96)
        X2[(long long)b * NN * 96 + t] = f2b((val - mean) * rstd * g[t] + beta[t]);
}

// ---------------- SoftmaxAggregation pooling: per (b,c) online softmax over N
__global__ __launch_bounds__(384) void k_pool(
    const ushort_t* __restrict__ X, const float* __restrict__ tptr,
    float* __restrict__ pooled) {
    int b = blockIdx.x;
    int c = threadIdx.x % 96, stripe = threadIdx.x / 96;
    float tv = tptr[0];
    float m = -1e30f, s = 0.f, w = 0.f;
    for (int n = stripe; n < NN; n += 4) {
        float x = b2f(X[((long long)b * NN + n) * 96 + c]);
        float sm = tv * x;
        if (sm > m) {
            float sc = expf(m - sm);
            s *= sc; w *= sc; m = sm;
        }
        float p = expf(sm - m);
        s += p; w += p * x;
    }
    __shared__ float ms[4][96], ss[4][96], wsh[4][96];
    ms[stripe][c] = m; ss[stripe][c] = s; wsh[stripe][c] = w;
    __syncthreads();
    if (threadIdx.x < 96) {
        float M = fmaxf(fmaxf(ms[0][c], ms[1][c]), fmaxf(ms[2][c], ms[3][c]));
        float S = 0.f, W = 0.f;
#pragma unroll
        for (int k = 0; k < 4; k++) {
            float sc = expf(ms[k][c] - M);
            S += ss[k][c] * sc;
            W += wsh[k][c] * sc;
        }
        pooled[b * 96 + c] = W / S;
    }
}

// ---------------- final: out = LN(gelu(pooled @ W_out + b_out)) -> [Bc,256]
__global__ __launch_bounds__(256) void k_out(
    const float* __restrict__ pooled, const float* __restrict__ W,
    const float* __restrict__ bias, const float* __restrict__ g,
    const float* __restrict__ beta, float* __restrict__ out) {
    int b = blockIdx.x, c = threadIdx.x;
    __shared__ float ps[96];
    __shared__ float rs[4], rq[4];
    if (c < 96) ps[c] = pooled[b * 96 + c];
    __syncthreads();
    float acc = bias[c];
    for (int k = 0; k < 96; k++) acc = fmaf(ps[k], W[k * 256 + c], acc);
    float v = gelu_f(acc);
    float s = v, sq = v * v;
#pragma unroll
    for (int mk = 32; mk >= 1; mk >>= 1) { s += __shfl_xor(s, mk, 64); sq += __shfl_xor(sq, mk, 64); }
    if ((c & 63) == 0) { rs[c >> 6] = s; rq[c >> 6] = sq; }
    __syncthreads();
    s = rs[0] + rs[1] + rs[2] + rs[3];
    sq = rq[0] + rq[1] + rq[2] + rq[3];
    float mean = s * (1.f / 256.f);
    float var = sq * (1.f / 256.f) - mean * mean;
    float rstd = rsqrtf(var + 1e-5f);
    out[b * 256 + c] = (v - mean) * rstd * g[c] + beta[c];
}

extern "C" void kernel_launch(void* const* d_in, const int* in_sizes, int n_in,
                              void* d_out, int out_size, void* d_ws, size_t ws_size,
                              hipStream_t stream) {
    const float* in0    = (const float*)d_in[0];
    const float* W_node = (const float*)d_in[1];
    const float* b_node = (const float*)d_in[2];
    const float* lnn_g  = (const float*)d_in[3];
    const float* lnn_b  = (const float*)d_in[4];
    const float* Wl1 = (const float*)d_in[5];
    const float* bl1 = (const float*)d_in[6];
    const float* Wr1 = (const float*)d_in[7];
    const float* br1 = (const float*)d_in[8];
    const float* att1 = (const float*)d_in[9];
    const float* bias1 = (const float*)d_in[10];
    const float* lnc1_g = (const float*)d_in[11];
    const float* lnc1_b = (const float*)d_in[12];
    const float* Wl2 = (const float*)d_in[13];
    const float* bl2 = (const float*)d_in[14];
    const float* Wr2 = (const float*)d_in[15];
    const float* br2 = (const float*)d_in[16];
    const float* att2 = (const float*)d_in[17];
    const float* bias2 = (const float*)d_in[18];
    const float* lnc2_g = (const float*)d_in[19];
    const float* lnc2_b = (const float*)d_in[20];
    const float* tptr = (const float*)d_in[21];
    const float* W_out = (const float*)d_in[22];
    const float* b_out = (const float*)d_in[23];
    const float* lno_g = (const float*)d_in[24];
    const float* lno_b = (const float*)d_in[25];

    // ---- batch chunking so scratch fits any ws_size ----
    auto alignup = [](size_t x) { return (x + 255) & ~(size_t)255; };
    auto need = [&](int bc) -> size_t {
        size_t rn = (size_t)bc * NN;
        return alignup(rn * 128 * 2)      // X  bf16
             + alignup(rn * 96 * 2)       // XL bf16
             + alignup(rn * 96 * 2)       // X2 bf16
             + alignup(rn * 3 * 4)        // scores f32
             + 3 * alignup((size_t)bc * 96 * 4);  // xr0,out0,pool f32
    };
    int bc = BB;
    while (bc > 1 && need(bc) > ws_size) bc >>= 1;

    for (int cb = 0; cb < BB; cb += bc) {
        size_t rn = (size_t)bc * NN;
        char* p = (char*)d_ws;
        ushort_t* Xbuf  = (ushort_t*)p; p += alignup(rn * 128 * 2);
        ushort_t* XLbuf = (ushort_t*)p; p += alignup(rn * 96 * 2);
        ushort_t* X2buf = (ushort_t*)p; p += alignup(rn * 96 * 2);
        float*    scbuf = (float*)p;    p += alignup(rn * 3 * 4);
        float*    xr0b  = (float*)p;    p += alignup((size_t)bc * 96 * 4);
        float*    out0b = (float*)p;    p += alignup((size_t)bc * 96 * 4);
        float*    poolb = (float*)p;

        const float* inC = in0 + (size_t)cb * NN * FIN;
        float* outC = (float*)d_out + (size_t)cb * 256;

        k_fcnode<<<bc * NN / 8, 256, 0, stream>>>(inC, W_node, b_node, lnn_g, lnn_b, Xbuf);

        // conv1
        k_xr0<128><<<bc, 128, 0, stream>>>(Xbuf, Wr1, br1, xr0b);
        k_conv<128><<<bc * NN / 32, 256, 0, stream>>>(Xbuf, Wl1, bl1, att1, xr0b, bias1,
                                                      lnc1_g, lnc1_b, XLbuf, scbuf, X2buf);
        k_agg<<<bc * 3, 256, 0, stream>>>(scbuf, XLbuf, out0b);
        k_row0<<<bc, 128, 0, stream>>>(out0b, bias1, lnc1_g, lnc1_b, X2buf);

        // conv2
        k_xr0<96><<<bc, 128, 0, stream>>>(X2buf, Wr2, br2, xr0b);
        k_conv<96><<<bc * NN / 32, 256, 0, stream>>>(X2buf, Wl2, bl2, att2, xr0b, bias2,
                                                     lnc2_g, lnc2_b, XLbuf, scbuf, Xbuf);
        k_agg<<<bc * 3, 256, 0, stream>>>(scbuf, XLbuf, out0b);
        k_row0<<<bc, 128, 0, stream>>>(out0b, bias2, lnc2_g, lnc2_b, Xbuf);

        // pooling + output head
        k_pool<<<bc, 384, 0, stream>>>(Xbuf, tptr, poolb);
        k_out<<<bc, 256, 0, stream>>>(poolb, W_out, b_out, lno_g, lno_b, outC);
    }
}

// Round 3
// 486.539 us; speedup vs baseline: 1.5548x; 1.5548x over previous
//
#include <hip/hip_runtime.h>
#include <hip/hip_bf16.h>
#include <math.h>

#define BB 128
#define NN 2048
#define FIN 17

typedef unsigned short ushort_t;
typedef __attribute__((ext_vector_type(8))) unsigned short u16x8;
typedef __attribute__((ext_vector_type(4))) unsigned short u16x4;
typedef __attribute__((ext_vector_type(8))) short s16x8;
typedef __attribute__((ext_vector_type(4))) float f32x4;

__device__ __forceinline__ float b2f(unsigned short u) {
    unsigned int v = ((unsigned int)u) << 16;
    return __builtin_bit_cast(float, v);
}
__device__ __forceinline__ unsigned short f2b(float f) {
    __hip_bfloat16 h = __float2bfloat16(f);
    return __builtin_bit_cast(unsigned short, h);
}
__device__ __forceinline__ float gelu_f(float x) {
    return 0.5f * x * (1.0f + erff(x * 0.70710678118654752f));
}
__device__ __forceinline__ float lrelu_f(float x) {
    return x >= 0.0f ? x : 0.2f * x;
}

// ---------------- Stage 1: x = LN(gelu(in @ W_node + b_node)) -> [Bc*N,128] bf16
__global__ __launch_bounds__(256) void k_fcnode(
    const float* __restrict__ X, const float* __restrict__ W,
    const float* __restrict__ bias, const float* __restrict__ g,
    const float* __restrict__ beta, ushort_t* __restrict__ out) {
    __shared__ float Wt[4][FIN][32];   // Wt[j][k][lane] = W[k][4*lane+j]
    __shared__ float bl[128], gl[128], bet[128];
    __shared__ float xrow[8][20];
    for (int i = threadIdx.x; i < FIN * 128; i += 256) {
        int k = i >> 7, c = i & 127;
        Wt[c & 3][k][c >> 2] = W[i];
    }
    if (threadIdx.x < 128) {
        bl[threadIdx.x] = bias[threadIdx.x];
        gl[threadIdx.x] = g[threadIdx.x];
        bet[threadIdx.x] = beta[threadIdx.x];
    }
    int grp = threadIdx.x >> 5, lane = threadIdx.x & 31;
    int row = blockIdx.x * 8 + grp;
    if (lane < FIN) xrow[grp][lane] = X[(long long)row * FIN + lane];
    __syncthreads();
    float acc[4] = {0.f, 0.f, 0.f, 0.f};
#pragma unroll
    for (int k = 0; k < FIN; k++) {
        float xv = xrow[grp][k];
#pragma unroll
        for (int j = 0; j < 4; j++) acc[j] = fmaf(xv, Wt[j][k][lane], acc[j]);
    }
    float v[4], s = 0.f, sq = 0.f;
#pragma unroll
    for (int j = 0; j < 4; j++) {
        v[j] = gelu_f(acc[j] + bl[4 * lane + j]);
        s += v[j]; sq += v[j] * v[j];
    }
#pragma unroll
    for (int m = 16; m >= 1; m >>= 1) { s += __shfl_xor(s, m, 32); sq += __shfl_xor(sq, m, 32); }
    float mean = s * (1.f / 128.f);
    float var = sq * (1.f / 128.f) - mean * mean;
    float rstd = rsqrtf(var + 1e-5f);
    u16x4 o4;
#pragma unroll
    for (int j = 0; j < 4; j++) {
        int c = 4 * lane + j;
        o4[j] = f2b((v[j] - mean) * rstd * gl[c] + bet[c]);
    }
    *(u16x4*)(out + (long long)row * 128 + 4 * lane) = o4;
}

// ---------------- W fragment prep: f32 [K,96] -> bf16 hi/lo in MFMA B-lane layout
template <int K>
__global__ __launch_bounds__(256) void k_wprep(
    const float* __restrict__ W, ushort_t* __restrict__ hi, ushort_t* __restrict__ lo) {
    constexpr int S = K / 32;
    int gid = blockIdx.x * 256 + threadIdx.x;
    if (gid >= 6 * S * 64) return;
    int lane = gid & 63, f = gid >> 6;
    int t = f / S, s = f - t * S;
    int n = 16 * t + (lane & 15);
    int kbase = 32 * s + 8 * (lane >> 4);
#pragma unroll
    for (int j = 0; j < 8; j++) {
        float w = W[(kbase + j) * 96 + n];
        ushort_t h = f2b(w);
        float rem = w - b2f(h);
        hi[gid * 8 + j] = h;
        lo[gid * 8 + j] = f2b(rem);
    }
}

// ---------------- xr0[b] = X[b,0,:] @ Wr + br  -> [Bc,96] f32
template <int K>
__global__ __launch_bounds__(128) void k_xr0(
    const ushort_t* __restrict__ X, const float* __restrict__ Wr,
    const float* __restrict__ br, float* __restrict__ xr0) {
    int b = blockIdx.x, c = threadIdx.x;
    __shared__ float xs[K];
    if (threadIdx.x < K) xs[threadIdx.x] = b2f(X[(long long)b * NN * K + threadIdx.x]);
    __syncthreads();
    if (c >= 96) return;
    float acc = br[c];
    for (int k = 0; k < K; k++) acc = fmaf(xs[k], Wr[k * 96 + c], acc);
    xr0[b * 96 + c] = acc;
}

// ---------------- MFMA conv: xl = X@Wl+bl; scores; finalize rows n>0
// Block = 256 thr = 4 waves; wave handles 32 rows (2x 16-row MFMA sets), 96 cols.
template <int K>
__global__ __launch_bounds__(256) void k_conv(
    const ushort_t* __restrict__ X,     // [Bc*N,K] bf16
    const ushort_t* __restrict__ Whi,   // B-frags hi [6*S*64*8]
    const ushort_t* __restrict__ Wlo,   // B-frags lo
    const float* __restrict__ bl, const float* __restrict__ att,
    const float* __restrict__ xr0,      // [Bc,96]
    const float* __restrict__ bias, const float* __restrict__ lng,
    const float* __restrict__ lnb,
    ushort_t* __restrict__ XLraw,       // [Bc*N,96] bf16
    float* __restrict__ scores,         // [Bc*N,3]
    ushort_t* __restrict__ Xout)        // [Bc*N,96] bf16
{
    constexpr int S = K / 32;
    int tid = threadIdx.x;
    int wave = tid >> 6, lane = tid & 63;
    int hi4 = lane >> 4, cl = lane & 15;
    int row0 = blockIdx.x * 128 + wave * 32;
    int b = row0 >> 11;   // chunk-local batch (NN=2048)

    f32x4 acc[2][6] = {};
    const s16x8* Wh = (const s16x8*)Whi;
    const s16x8* Wl8 = (const s16x8*)Wlo;
#pragma unroll
    for (int s = 0; s < S; s++) {
        s16x8 a0 = *(const s16x8*)(X + (size_t)(row0 + cl) * K + s * 32 + hi4 * 8);
        s16x8 a1 = *(const s16x8*)(X + (size_t)(row0 + 16 + cl) * K + s * 32 + hi4 * 8);
#pragma unroll
        for (int t = 0; t < 6; t++) {
            s16x8 bh = Wh[(t * S + s) * 64 + lane];
            s16x8 bo = Wl8[(t * S + s) * 64 + lane];
            acc[0][t] = __builtin_amdgcn_mfma_f32_16x16x32_bf16(a0, bh, acc[0][t], 0, 0, 0);
            acc[0][t] = __builtin_amdgcn_mfma_f32_16x16x32_bf16(a0, bo, acc[0][t], 0, 0, 0);
            acc[1][t] = __builtin_amdgcn_mfma_f32_16x16x32_bf16(a1, bh, acc[1][t], 0, 0, 0);
            acc[1][t] = __builtin_amdgcn_mfma_f32_16x16x32_bf16(a1, bo, acc[1][t], 0, 0, 0);
        }
    }

    // per-lane params for its 6 channels c = 16t + cl
    float blc[6], xrc[6], attc[6], bic[6], gc[6], bcc[6];
#pragma unroll
    for (int t = 0; t < 6; t++) {
        int c = 16 * t + cl;
        blc[t] = bl[c]; xrc[t] = xr0[b * 96 + c]; attc[t] = att[c];
        bic[t] = bias[c]; gc[t] = lng[c]; bcc[t] = lnb[c];
    }

#pragma unroll
    for (int q = 0; q < 2; q++) {
#pragma unroll
        for (int i = 0; i < 4; i++) {
            int row = row0 + q * 16 + hi4 * 4 + i;
            float xl[6];
#pragma unroll
            for (int t = 0; t < 6; t++) xl[t] = acc[q][t][i] + blc[t];
            // XL raw store (for aggregation)
#pragma unroll
            for (int t = 0; t < 6; t++)
                XLraw[(size_t)row * 96 + 16 * t + cl] = f2b(xl[t]);
            // attention scores (3 heads; n-tile t belongs to head t>>1)
            float pv[6];
#pragma unroll
            for (int t = 0; t < 6; t++) pv[t] = attc[t] * lrelu_f(xl[t] + xrc[t]);
            float p0 = pv[0] + pv[1], p1 = pv[2] + pv[3], p2 = pv[4] + pv[5];
#pragma unroll
            for (int mk = 1; mk <= 8; mk <<= 1) {
                p0 += __shfl_xor(p0, mk, 64);
                p1 += __shfl_xor(p1, mk, 64);
                p2 += __shfl_xor(p2, mk, 64);
            }
            if (cl < 3) {
                float sv = (cl == 0) ? p0 : ((cl == 1) ? p1 : p2);
                scores[(size_t)row * 3 + cl] = sv;
            }
            // gelu + LN for rows n>0
            float o[6], s = 0.f, sq = 0.f;
#pragma unroll
            for (int t = 0; t < 6; t++) {
                o[t] = gelu_f(xl[t] + bic[t]);
                s += o[t]; sq += o[t] * o[t];
            }
#pragma unroll
            for (int mk = 1; mk <= 8; mk <<= 1) {
                s += __shfl_xor(s, mk, 64);
                sq += __shfl_xor(sq, mk, 64);
            }
            float mean = s * (1.f / 96.f);
            float var = sq * (1.f / 96.f) - mean * mean;
            float rstd = rsqrtf(var + 1e-5f);
            if ((row & (NN - 1)) != 0) {
#pragma unroll
                for (int t = 0; t < 6; t++)
                    Xout[(size_t)row * 96 + 16 * t + cl] =
                        f2b((o[t] - mean) * rstd * gc[t] + bcc[t]);
            }
        }
    }
}

// ---------------- per-(b,h): softmax over N scores, out0 = sum alpha*xl
__global__ __launch_bounds__(256) void k_agg(
    const float* __restrict__ scores, const ushort_t* __restrict__ XL,
    float* __restrict__ out0) {
    int b = blockIdx.x / 3, h = blockIdx.x - b * 3;
    __shared__ float als[NN];
    __shared__ float red[4];
    __shared__ float Zs;
    __shared__ float racc[8][33];
    int tid = threadIdx.x;
    const float* sb = scores + (long long)b * NN * 3 + h;
    float m = -1e30f;
    for (int n = tid; n < NN; n += 256) m = fmaxf(m, sb[n * 3]);
#pragma unroll
    for (int mk = 32; mk >= 1; mk >>= 1) m = fmaxf(m, __shfl_xor(m, mk, 64));
    if ((tid & 63) == 0) red[tid >> 6] = m;
    __syncthreads();
    m = fmaxf(fmaxf(red[0], red[1]), fmaxf(red[2], red[3]));
    __syncthreads();
    float s = 0.f;
    for (int n = tid; n < NN; n += 256) {
        float e = expf(sb[n * 3] - m);
        als[n] = e;
        s += e;
    }
#pragma unroll
    for (int mk = 32; mk >= 1; mk >>= 1) s += __shfl_xor(s, mk, 64);
    if ((tid & 63) == 0) red[tid >> 6] = s;
    __syncthreads();
    if (tid == 0) Zs = red[0] + red[1] + red[2] + red[3];
    int cl = tid & 31, ns = tid >> 5;
    float acc = 0.f;
    const ushort_t* xb = XL + (long long)b * NN * 96 + h * 32 + cl;
    for (int n = ns; n < NN; n += 8) acc += als[n] * b2f(xb[(long long)n * 96]);
    racc[ns][cl] = acc;
    __syncthreads();
    if (tid < 32) {
        float a = 0.f;
#pragma unroll
        for (int k = 0; k < 8; k++) a += racc[k][tid];
        out0[b * 96 + tid + h * 32] = a / Zs;
    }
}

// ---------------- finalize node-0 row: X2[b,0,:] = LN(gelu(out0 + bias))
__global__ __launch_bounds__(128) void k_row0(
    const float* __restrict__ out0, const float* __restrict__ bias,
    const float* __restrict__ g, const float* __restrict__ beta,
    ushort_t* __restrict__ X2) {
    int b = blockIdx.x, t = threadIdx.x;
    __shared__ float vv[96];
    __shared__ float red2[2];
    float val = 0.f;
    if (t < 96) {
        val = gelu_f(out0[b * 96 + t] + bias[t]);
        vv[t] = val;
    }
    __syncthreads();
    if (t < 32) {
        float a = vv[t], b2 = vv[t + 32], c = vv[t + 64];
        float s = a + b2 + c, sq = a * a + b2 * b2 + c * c;
#pragma unroll
        for (int mk = 16; mk >= 1; mk >>= 1) { s += __shfl_xor(s, mk, 32); sq += __shfl_xor(sq, mk, 32); }
        if (t == 0) { red2[0] = s; red2[1] = sq; }
    }
    __syncthreads();
    float mean = red2[0] * (1.f / 96.f);
    float var = red2[1] * (1.f / 96.f) - mean * mean;
    float rstd = rsqrtf(var + 1e-5f);
    if (t < 96)
        X2[(long long)b * NN * 96 + t] = f2b((val - mean) * rstd * g[t] + beta[t]);
}

// ---------------- pooling partials: grid Bc*8; online softmax over n-stripe
__global__ __launch_bounds__(128) void k_pool1(
    const ushort_t* __restrict__ X, const float* __restrict__ tptr,
    float* __restrict__ part) {
    int b = blockIdx.x >> 3, q = blockIdx.x & 7;
    int c = threadIdx.x;
    if (c >= 96) return;
    float tv = tptr[0];
    float m = -1e30f, s = 0.f, w = 0.f;
    for (int n = q; n < NN; n += 8) {
        float x = b2f(X[((long long)b * NN + n) * 96 + c]);
        float sm = tv * x;
        if (sm > m) {
            float sc = expf(m - sm);
            s *= sc; w *= sc; m = sm;
        }
        float p = expf(sm - m);
        s += p; w += p * x;
    }
    float* p = part + ((size_t)(b * 8 + q) * 96 + c) * 3;
    p[0] = m; p[1] = s; p[2] = w;
}

// ---------------- pooling combine
__global__ __launch_bounds__(128) void k_pool2(
    const float* __restrict__ part, float* __restrict__ pooled) {
    int b = blockIdx.x, c = threadIdx.x;
    if (c >= 96) return;
    float M = -1e30f, S = 0.f, W = 0.f;
#pragma unroll
    for (int q = 0; q < 8; q++) {
        const float* p = part + ((size_t)(b * 8 + q) * 96 + c) * 3;
        float m = p[0], s = p[1], w = p[2];
        float M2 = fmaxf(M, m);
        float scA = expf(M - M2), scB = expf(m - M2);
        S = S * scA + s * scB;
        W = W * scA + w * scB;
        M = M2;
    }
    pooled[b * 96 + c] = W / S;
}

// ---------------- final: out = LN(gelu(pooled @ W_out + b_out)) -> [Bc,256]
__global__ __launch_bounds__(256) void k_out(
    const float* __restrict__ pooled, const float* __restrict__ W,
    const float* __restrict__ bias, const float* __restrict__ g,
    const float* __restrict__ beta, float* __restrict__ out) {
    int b = blockIdx.x, c = threadIdx.x;
    __shared__ float ps[96];
    __shared__ float rs[4], rq[4];
    if (c < 96) ps[c] = pooled[b * 96 + c];
    __syncthreads();
    float acc = bias[c];
    for (int k = 0; k < 96; k++) acc = fmaf(ps[k], W[k * 256 + c], acc);
    float v = gelu_f(acc);
    float s = v, sq = v * v;
#pragma unroll
    for (int mk = 32; mk >= 1; mk >>= 1) { s += __shfl_xor(s, mk, 64); sq += __shfl_xor(sq, mk, 64); }
    if ((c & 63) == 0) { rs[c >> 6] = s; rq[c >> 6] = sq; }
    __syncthreads();
    s = rs[0] + rs[1] + rs[2] + rs[3];
    sq = rq[0] + rq[1] + rq[2] + rq[3];
    float mean = s * (1.f / 256.f);
    float var = sq * (1.f / 256.f) - mean * mean;
    float rstd = rsqrtf(var + 1e-5f);
    out[b * 256 + c] = (v - mean) * rstd * g[c] + beta[c];
}

extern "C" void kernel_launch(void* const* d_in, const int* in_sizes, int n_in,
                              void* d_out, int out_size, void* d_ws, size_t ws_size,
                              hipStream_t stream) {
    const float* in0    = (const float*)d_in[0];
    const float* W_node = (const float*)d_in[1];
    const float* b_node = (const float*)d_in[2];
    const float* lnn_g  = (const float*)d_in[3];
    const float* lnn_b  = (const float*)d_in[4];
    const float* Wl1 = (const float*)d_in[5];
    const float* bl1 = (const float*)d_in[6];
    const float* Wr1 = (const float*)d_in[7];
    const float* br1 = (const float*)d_in[8];
    const float* att1 = (const float*)d_in[9];
    const float* bias1 = (const float*)d_in[10];
    const float* lnc1_g = (const float*)d_in[11];
    const float* lnc1_b = (const float*)d_in[12];
    const float* Wl2 = (const float*)d_in[13];
    const float* bl2 = (const float*)d_in[14];
    const float* Wr2 = (const float*)d_in[15];
    const float* br2 = (const float*)d_in[16];
    const float* att2 = (const float*)d_in[17];
    const float* bias2 = (const float*)d_in[18];
    const float* lnc2_g = (const float*)d_in[19];
    const float* lnc2_b = (const float*)d_in[20];
    const float* tptr = (const float*)d_in[21];
    const float* W_out = (const float*)d_in[22];
    const float* b_out = (const float*)d_in[23];
    const float* lno_g = (const float*)d_in[24];
    const float* lno_b = (const float*)d_in[25];

    auto alignup = [](size_t x) { return (x + 255) & ~(size_t)255; };

    // fixed region: MFMA B-fragments (hi/lo) for both conv layers
    const size_t wf1 = (size_t)6 * 4 * 64 * 8;  // K=128: elements per buffer
    const size_t wf2 = (size_t)6 * 3 * 64 * 8;  // K=96
    char* base = (char*)d_ws;
    ushort_t* wf1h = (ushort_t*)base;             base += alignup(wf1 * 2);
    ushort_t* wf1l = (ushort_t*)base;             base += alignup(wf1 * 2);
    ushort_t* wf2h = (ushort_t*)base;             base += alignup(wf2 * 2);
    ushort_t* wf2l = (ushort_t*)base;             base += alignup(wf2 * 2);
    size_t fixed = (size_t)(base - (char*)d_ws);

    auto need = [&](int bcx) -> size_t {
        size_t rn = (size_t)bcx * NN;
        return fixed
             + alignup(rn * 128 * 2)                 // X bf16
             + alignup(rn * 96 * 2)                  // XL bf16
             + alignup(rn * 96 * 2)                  // X2 bf16
             + alignup(rn * 3 * 4)                   // scores f32
             + 3 * alignup((size_t)bcx * 96 * 4)     // xr0,out0,pooled
             + alignup((size_t)bcx * 8 * 96 * 3 * 4);// pool partials
    };
    int bc = BB;
    while (bc > 1 && need(bc) > ws_size) bc >>= 1;

    k_wprep<128><<<6, 256, 0, stream>>>(Wl1, wf1h, wf1l);
    k_wprep<96><<<5, 256, 0, stream>>>(Wl2, wf2h, wf2l);

    for (int cb = 0; cb < BB; cb += bc) {
        size_t rn = (size_t)bc * NN;
        char* p = base;
        ushort_t* Xbuf  = (ushort_t*)p; p += alignup(rn * 128 * 2);
        ushort_t* XLbuf = (ushort_t*)p; p += alignup(rn * 96 * 2);
        ushort_t* X2buf = (ushort_t*)p; p += alignup(rn * 96 * 2);
        float*    scbuf = (float*)p;    p += alignup(rn * 3 * 4);
        float*    xr0b  = (float*)p;    p += alignup((size_t)bc * 96 * 4);
        float*    out0b = (float*)p;    p += alignup((size_t)bc * 96 * 4);
        float*    poolb = (float*)p;    p += alignup((size_t)bc * 96 * 4);
        float*    partb = (float*)p;

        const float* inC = in0 + (size_t)cb * NN * FIN;
        float* outC = (float*)d_out + (size_t)cb * 256;

        k_fcnode<<<bc * NN / 8, 256, 0, stream>>>(inC, W_node, b_node, lnn_g, lnn_b, Xbuf);

        // conv1
        k_xr0<128><<<bc, 128, 0, stream>>>(Xbuf, Wr1, br1, xr0b);
        k_conv<128><<<bc * NN / 128, 256, 0, stream>>>(Xbuf, wf1h, wf1l, bl1, att1, xr0b,
                                                       bias1, lnc1_g, lnc1_b, XLbuf, scbuf, X2buf);
        k_agg<<<bc * 3, 256, 0, stream>>>(scbuf, XLbuf, out0b);
        k_row0<<<bc, 128, 0, stream>>>(out0b, bias1, lnc1_g, lnc1_b, X2buf);

        // conv2
        k_xr0<96><<<bc, 128, 0, stream>>>(X2buf, Wr2, br2, xr0b);
        k_conv<96><<<bc * NN / 128, 256, 0, stream>>>(X2buf, wf2h, wf2l, bl2, att2, xr0b,
                                                      bias2, lnc2_g, lnc2_b, XLbuf, scbuf, Xbuf);
        k_agg<<<bc * 3, 256, 0, stream>>>(scbuf, XLbuf, out0b);
        k_row0<<<bc, 128, 0, stream>>>(out0b, bias2, lnc2_g, lnc2_b, Xbuf);

        // pooling + output head
        k_pool1<<<bc * 8, 128, 0, stream>>>(Xbuf, tptr, partb);
        k_pool2<<<bc, 128, 0, stream>>>(partb, poolb);
        k_out<<<bc, 256, 0, stream>>>(poolb, W_out, b_out, lno_g, lno_b, outC);
    }
}

// Round 6
// 238.869 us; speedup vs baseline: 3.1668x; 2.0368x over previous
//
#include <hip/hip_runtime.h>
#include <hip/hip_bf16.h>
#include <math.h>

#define BB 128
#define NN 2048
#define FIN 17

#define SCALE_I 1048576.0f          // 2^20 fixed-point scale
#define INV_SCALE 9.5367431640625e-07f

typedef unsigned short ushort_t;
typedef unsigned long long ull_t;
typedef __attribute__((ext_vector_type(4))) unsigned short u16x4;
typedef __attribute__((ext_vector_type(8))) short s16x8;
typedef __attribute__((ext_vector_type(4))) float f32x4;

__device__ __forceinline__ float b2f(unsigned short u) {
    unsigned int v = ((unsigned int)u) << 16;
    return __builtin_bit_cast(float, v);
}
__device__ __forceinline__ unsigned short f2b(float f) {
    __hip_bfloat16 h = __float2bfloat16(f);
    return __builtin_bit_cast(unsigned short, h);
}
// gelu via A&S 7.1.26 erf approx (|abs err| <= 1.5e-7)
__device__ __forceinline__ float gelu_f(float x) {
    float ax = fabsf(x) * 0.70710678118654752f;
    float t = 1.0f / (1.0f + 0.3275911f * ax);
    float poly = t * (0.254829592f +
                 t * (-0.284496736f +
                 t * (1.421413741f +
                 t * (-1.453152027f +
                 t * 1.061405429f))));
    float erfv = 1.0f - poly * __expf(-ax * ax);
    erfv = (x >= 0.f) ? erfv : -erfv;
    return 0.5f * x * (1.0f + erfv);
}
__device__ __forceinline__ float lrelu_f(float x) {
    return x >= 0.0f ? x : 0.2f * x;
}
__device__ __forceinline__ ull_t q20(float x) {
    return (ull_t)(long long)(x * SCALE_I);
}

// ---------------- zero integer accumulators
__global__ __launch_bounds__(256) void k_zero64(ull_t* __restrict__ p, int n) {
    int i = blockIdx.x * 256 + threadIdx.x;
    if (i < n) p[i] = 0ull;
}

// ---------------- Stage 1: x = LN(gelu(in @ W_node + b_node)) -> [Bc*N,128] bf16
__global__ __launch_bounds__(256) void k_fcnode(
    const float* __restrict__ X, const float* __restrict__ W,
    const float* __restrict__ bias, const float* __restrict__ g,
    const float* __restrict__ beta, ushort_t* __restrict__ out) {
    __shared__ float Ws[FIN * 128];
    __shared__ float xs[64 * FIN];
    __shared__ float bl[128], gl[128], bet[128];
    int tid = threadIdx.x;
    long long rbase = (long long)blockIdx.x * 64;
    for (int i = tid; i < FIN * 128; i += 256) Ws[i] = W[i];
    for (int i = tid; i < 64 * FIN; i += 256) xs[i] = X[rbase * FIN + i];
    if (tid < 128) {
        bl[tid] = bias[tid]; gl[tid] = g[tid]; bet[tid] = beta[tid];
    }
    __syncthreads();
    int lane32 = tid & 31, sub = tid >> 5;
    int c0 = 4 * lane32;
    f32x4 acc[8] = {};
#pragma unroll
    for (int k = 0; k < FIN; k++) {
        f32x4 w = *(const f32x4*)(Ws + k * 128 + c0);
#pragma unroll
        for (int r = 0; r < 8; r++) {
            float xv = xs[(sub + 8 * r) * FIN + k];
            acc[r][0] = fmaf(xv, w[0], acc[r][0]);
            acc[r][1] = fmaf(xv, w[1], acc[r][1]);
            acc[r][2] = fmaf(xv, w[2], acc[r][2]);
            acc[r][3] = fmaf(xv, w[3], acc[r][3]);
        }
    }
#pragma unroll
    for (int r = 0; r < 8; r++) {
        int lr = sub + 8 * r;
        float v[4], s = 0.f, sq = 0.f;
#pragma unroll
        for (int j = 0; j < 4; j++) {
            v[j] = gelu_f(acc[r][j] + bl[c0 + j]);
            s += v[j]; sq += v[j] * v[j];
        }
#pragma unroll
        for (int mk = 16; mk >= 1; mk >>= 1) {
            s += __shfl_xor(s, mk, 32); sq += __shfl_xor(sq, mk, 32);
        }
        float mean = s * (1.f / 128.f);
        float var = sq * (1.f / 128.f) - mean * mean;
        float rstd = rsqrtf(var + 1e-5f);
        u16x4 o4;
#pragma unroll
        for (int j = 0; j < 4; j++)
            o4[j] = f2b((v[j] - mean) * rstd * gl[c0 + j] + bet[c0 + j]);
        *(u16x4*)(out + (rbase + lr) * 128 + c0) = o4;
    }
}

// ---------------- W fragment prep: f32 [K,96] -> bf16 hi/lo in MFMA B-lane layout
template <int K>
__global__ __launch_bounds__(256) void k_wprep(
    const float* __restrict__ W, ushort_t* __restrict__ hi, ushort_t* __restrict__ lo) {
    constexpr int S = K / 32;
    int gid = blockIdx.x * 256 + threadIdx.x;
    if (gid >= 6 * S * 64) return;
    int lane = gid & 63, f = gid >> 6;
    int t = f / S, s = f - t * S;
    int n = 16 * t + (lane & 15);
    int kbase = 32 * s + 8 * (lane >> 4);
#pragma unroll
    for (int j = 0; j < 8; j++) {
        float w = W[(kbase + j) * 96 + n];
        ushort_t h = f2b(w);
        float rem = w - b2f(h);
        hi[gid * 8 + j] = h;
        lo[gid * 8 + j] = f2b(rem);
    }
}

// ---------------- xr0[b] = X[b,0,:] @ Wr + br  -> [Bc,96] f32
template <int K>
__global__ __launch_bounds__(128) void k_xr0(
    const ushort_t* __restrict__ X, const float* __restrict__ Wr,
    const float* __restrict__ br, float* __restrict__ xr0) {
    int b = blockIdx.x, c = threadIdx.x;
    __shared__ float xs[K];
    if (threadIdx.x < K) xs[threadIdx.x] = b2f(X[(long long)b * NN * K + threadIdx.x]);
    __syncthreads();
    if (c >= 96) return;
    float acc = br[c];
    for (int k = 0; k < K; k++) acc = fmaf(xs[k], Wr[k * 96 + c], acc);
    xr0[b * 96 + c] = acc;
}

// ---------------- MFMA conv with fused attention (+pool) accumulation.
// Block = 256 thr = 4 waves; wave: 32 rows x 96 cols. DETERMINISTIC via
// integer fixed-point atomics (exactly commutative).
template <int K, bool POOLF>
__global__ __launch_bounds__(256) void k_conv(
    const ushort_t* __restrict__ X,     // [Bc*N,K] bf16
    const ushort_t* __restrict__ Whi, const ushort_t* __restrict__ Wlo,
    const float* __restrict__ bl, const float* __restrict__ att,
    const float* __restrict__ xr0,      // [Bc,96]
    const float* __restrict__ bias, const float* __restrict__ lng,
    const float* __restrict__ lnb,
    ull_t* __restrict__ w0acc,          // [Bc*96]  fixed-point sum e*xl
    ull_t* __restrict__ zacc,           // [Bc*4]   fixed-point sum e per head
    ushort_t* __restrict__ Xout,        // layer1: [Bc*N,96] bf16
    ull_t* __restrict__ pacc,           // layer2: [Bc*192] (ps | pw) fixed-point
    const float* __restrict__ tptr)
{
    constexpr int S = K / 32;
    int tid = threadIdx.x;
    int wave = tid >> 6, lane = tid & 63;
    int hi4 = lane >> 4, cl = lane & 15;
    int row0 = blockIdx.x * 128 + wave * 32;
    int b = row0 >> 11;

    f32x4 acc[2][6] = {};
    const s16x8* Wh = (const s16x8*)Whi;
    const s16x8* Wl8 = (const s16x8*)Wlo;
#pragma unroll
    for (int s = 0; s < S; s++) {
        s16x8 a0 = *(const s16x8*)(X + (size_t)(row0 + cl) * K + s * 32 + hi4 * 8);
        s16x8 a1 = *(const s16x8*)(X + (size_t)(row0 + 16 + cl) * K + s * 32 + hi4 * 8);
#pragma unroll
        for (int t = 0; t < 6; t++) {
            s16x8 bh = Wh[(t * S + s) * 64 + lane];
            s16x8 bo = Wl8[(t * S + s) * 64 + lane];
            acc[0][t] = __builtin_amdgcn_mfma_f32_16x16x32_bf16(a0, bh, acc[0][t], 0, 0, 0);
            acc[0][t] = __builtin_amdgcn_mfma_f32_16x16x32_bf16(a0, bo, acc[0][t], 0, 0, 0);
            acc[1][t] = __builtin_amdgcn_mfma_f32_16x16x32_bf16(a1, bh, acc[1][t], 0, 0, 0);
            acc[1][t] = __builtin_amdgcn_mfma_f32_16x16x32_bf16(a1, bo, acc[1][t], 0, 0, 0);
        }
    }

    float blc[6], xrc[6], attc[6], bic[6], gc[6], bcc[6];
#pragma unroll
    for (int t = 0; t < 6; t++) {
        int c = 16 * t + cl;
        blc[t] = bl[c]; xrc[t] = xr0[b * 96 + c]; attc[t] = att[c];
        bic[t] = bias[c]; gc[t] = lng[c]; bcc[t] = lnb[c];
    }
    float tv = POOLF ? tptr[0] : 0.f;

    float w0p[6] = {0.f, 0.f, 0.f, 0.f, 0.f, 0.f};
    float zp[3] = {0.f, 0.f, 0.f};
    float psp[6] = {0.f, 0.f, 0.f, 0.f, 0.f, 0.f};
    float pwp[6] = {0.f, 0.f, 0.f, 0.f, 0.f, 0.f};

#pragma unroll
    for (int q = 0; q < 2; q++) {
#pragma unroll
        for (int i = 0; i < 4; i++) {
            int row = row0 + q * 16 + hi4 * 4 + i;
            float xl[6];
#pragma unroll
            for (int t = 0; t < 6; t++) xl[t] = acc[q][t][i] + blc[t];
            // attention scores per head
            float pv[6];
#pragma unroll
            for (int t = 0; t < 6; t++) pv[t] = attc[t] * lrelu_f(xl[t] + xrc[t]);
            float p0 = pv[0] + pv[1], p1 = pv[2] + pv[3], p2 = pv[4] + pv[5];
#pragma unroll
            for (int mk = 1; mk <= 8; mk <<= 1) {
                p0 += __shfl_xor(p0, mk, 64);
                p1 += __shfl_xor(p1, mk, 64);
                p2 += __shfl_xor(p2, mk, 64);
            }
            float e0 = __expf(fminf(p0, 24.f));
            float e1 = __expf(fminf(p1, 24.f));
            float e2 = __expf(fminf(p2, 24.f));
            w0p[0] = fmaf(e0, xl[0], w0p[0]); w0p[1] = fmaf(e0, xl[1], w0p[1]);
            w0p[2] = fmaf(e1, xl[2], w0p[2]); w0p[3] = fmaf(e1, xl[3], w0p[3]);
            w0p[4] = fmaf(e2, xl[4], w0p[4]); w0p[5] = fmaf(e2, xl[5], w0p[5]);
            zp[0] += e0; zp[1] += e1; zp[2] += e2;
            // output path: gelu + LN
            float o[6], s = 0.f, sq = 0.f;
#pragma unroll
            for (int t = 0; t < 6; t++) {
                o[t] = gelu_f(xl[t] + bic[t]);
                s += o[t]; sq += o[t] * o[t];
            }
#pragma unroll
            for (int mk = 1; mk <= 8; mk <<= 1) {
                s += __shfl_xor(s, mk, 64);
                sq += __shfl_xor(sq, mk, 64);
            }
            float mean = s * (1.f / 96.f);
            float var = sq * (1.f / 96.f) - mean * mean;
            float rstd = rsqrtf(var + 1e-5f);
            if ((row & (NN - 1)) != 0) {
                if (!POOLF) {
#pragma unroll
                    for (int t = 0; t < 6; t++)
                        Xout[(size_t)row * 96 + 16 * t + cl] =
                            f2b((o[t] - mean) * rstd * gc[t] + bcc[t]);
                } else {
#pragma unroll
                    for (int t = 0; t < 6; t++) {
                        float v = (o[t] - mean) * rstd * gc[t] + bcc[t];
                        float pe = __expf(fminf(tv * v, 24.f));
                        psp[t] += pe;
                        pwp[t] = fmaf(pe, v, pwp[t]);
                    }
                }
            }
        }
    }

    // reduce across the 4 hi4 groups (lanes cl, cl+16, cl+32, cl+48)
#pragma unroll
    for (int t = 0; t < 6; t++) {
        w0p[t] += __shfl_xor(w0p[t], 16, 64);
        w0p[t] += __shfl_xor(w0p[t], 32, 64);
    }
#pragma unroll
    for (int h = 0; h < 3; h++) {
        zp[h] += __shfl_xor(zp[h], 16, 64);
        zp[h] += __shfl_xor(zp[h], 32, 64);
    }
    if (POOLF) {
#pragma unroll
        for (int t = 0; t < 6; t++) {
            psp[t] += __shfl_xor(psp[t], 16, 64);
            psp[t] += __shfl_xor(psp[t], 32, 64);
            pwp[t] += __shfl_xor(pwp[t], 16, 64);
            pwp[t] += __shfl_xor(pwp[t], 32, 64);
        }
    }
    if (lane < 16) {
#pragma unroll
        for (int t = 0; t < 6; t++)
            atomicAdd(w0acc + b * 96 + 16 * t + lane, q20(w0p[t]));
        if (POOLF) {
#pragma unroll
            for (int t = 0; t < 6; t++) {
                atomicAdd(pacc + b * 192 + 16 * t + lane, q20(psp[t]));
                atomicAdd(pacc + b * 192 + 96 + 16 * t + lane, q20(pwp[t]));
            }
        }
    }
    if (lane == 0) {
        atomicAdd(zacc + b * 4 + 0, q20(zp[0]));
        atomicAdd(zacc + b * 4 + 1, q20(zp[1]));
        atomicAdd(zacc + b * 4 + 2, q20(zp[2]));
    }
}

// ---------------- finalize node-0 row: x0 = LN(gelu(w0acc/z + bias))
// LAYER 1: write X2 row 0 (bf16).  LAYER 2: write row-0 LN value to row0v.
template <int LAYER>
__global__ __launch_bounds__(128) void k_row0(
    const ull_t* __restrict__ w0acc, const ull_t* __restrict__ zacc,
    const float* __restrict__ bias, const float* __restrict__ g,
    const float* __restrict__ beta, ushort_t* __restrict__ X2,
    float* __restrict__ row0v) {
    int b = blockIdx.x, t = threadIdx.x;
    __shared__ float vv[96];
    __shared__ float red2[2];
    float val = 0.f;
    if (t < 96) {
        float wf = (float)(long long)w0acc[b * 96 + t];
        float zf = (float)(long long)zacc[b * 4 + (t >> 5)];
        float out0 = wf / zf;   // fixed-point scale cancels
        val = gelu_f(out0 + bias[t]);
        vv[t] = val;
    }
    __syncthreads();
    if (t < 32) {
        float a = vv[t], b2 = vv[t + 32], c = vv[t + 64];
        float s = a + b2 + c, sq = a * a + b2 * b2 + c * c;
#pragma unroll
        for (int mk = 16; mk >= 1; mk >>= 1) { s += __shfl_xor(s, mk, 32); sq += __shfl_xor(sq, mk, 32); }
        if (t == 0) { red2[0] = s; red2[1] = sq; }
    }
    __syncthreads();
    float mean = red2[0] * (1.f / 96.f);
    float var = red2[1] * (1.f / 96.f) - mean * mean;
    float rstd = rsqrtf(var + 1e-5f);
    if (t < 96) {
        float ln = (val - mean) * rstd * g[t] + beta[t];
        if (LAYER == 1) {
            X2[(long long)b * NN * 96 + t] = f2b(ln);
        } else {
            row0v[b * 96 + t] = ln;
        }
    }
}

// ---------------- final: pooled = (pw + row0 term)/(ps + row0 term);
// out = LN(gelu(pooled @ W_out + b_out)) -> [Bc,256]
__global__ __launch_bounds__(256) void k_out(
    const ull_t* __restrict__ pacc, const float* __restrict__ row0v,
    const float* __restrict__ tptr, const float* __restrict__ W,
    const float* __restrict__ bias, const float* __restrict__ g,
    const float* __restrict__ beta, float* __restrict__ out) {
    int b = blockIdx.x, c = threadIdx.x;
    __shared__ float ps[96];
    __shared__ float rs[4], rq[4];
    if (c < 96) {
        float ln0 = row0v[b * 96 + c];
        float pe0 = __expf(fminf(tptr[0] * ln0, 24.f));
        float S = (float)(long long)pacc[b * 192 + c] * INV_SCALE + pe0;
        float Wp = (float)(long long)pacc[b * 192 + 96 + c] * INV_SCALE + pe0 * ln0;
        ps[c] = Wp / S;
    }
    __syncthreads();
    float acc = bias[c];
    for (int k = 0; k < 96; k++) acc = fmaf(ps[k], W[k * 256 + c], acc);
    float v = gelu_f(acc);
    float s = v, sq = v * v;
#pragma unroll
    for (int mk = 32; mk >= 1; mk >>= 1) { s += __shfl_xor(s, mk, 64); sq += __shfl_xor(sq, mk, 64); }
    if ((c & 63) == 0) { rs[c >> 6] = s; rq[c >> 6] = sq; }
    __syncthreads();
    s = rs[0] + rs[1] + rs[2] + rs[3];
    sq = rq[0] + rq[1] + rq[2] + rq[3];
    float mean = s * (1.f / 256.f);
    float var = sq * (1.f / 256.f) - mean * mean;
    float rstd = rsqrtf(var + 1e-5f);
    out[b * 256 + c] = (v - mean) * rstd * g[c] + beta[c];
}

extern "C" void kernel_launch(void* const* d_in, const int* in_sizes, int n_in,
                              void* d_out, int out_size, void* d_ws, size_t ws_size,
                              hipStream_t stream) {
    const float* in0    = (const float*)d_in[0];
    const float* W_node = (const float*)d_in[1];
    const float* b_node = (const float*)d_in[2];
    const float* lnn_g  = (const float*)d_in[3];
    const float* lnn_b  = (const float*)d_in[4];
    const float* Wl1 = (const float*)d_in[5];
    const float* bl1 = (const float*)d_in[6];
    const float* Wr1 = (const float*)d_in[7];
    const float* br1 = (const float*)d_in[8];
    const float* att1 = (const float*)d_in[9];
    const float* bias1 = (const float*)d_in[10];
    const float* lnc1_g = (const float*)d_in[11];
    const float* lnc1_b = (const float*)d_in[12];
    const float* Wl2 = (const float*)d_in[13];
    const float* bl2 = (const float*)d_in[14];
    const float* Wr2 = (const float*)d_in[15];
    const float* br2 = (const float*)d_in[16];
    const float* att2 = (const float*)d_in[17];
    const float* bias2 = (const float*)d_in[18];
    const float* lnc2_g = (const float*)d_in[19];
    const float* lnc2_b = (const float*)d_in[20];
    const float* tptr = (const float*)d_in[21];
    const float* W_out = (const float*)d_in[22];
    const float* b_out = (const float*)d_in[23];
    const float* lno_g = (const float*)d_in[24];
    const float* lno_b = (const float*)d_in[25];

    auto alignup = [](size_t x) { return (x + 255) & ~(size_t)255; };

    // fixed region: MFMA B-fragments (hi/lo) for both conv layers
    const size_t wf1 = (size_t)6 * 4 * 64 * 8;  // K=128
    const size_t wf2 = (size_t)6 * 3 * 64 * 8;  // K=96
    char* base = (char*)d_ws;
    ushort_t* wf1h = (ushort_t*)base;             base += alignup(wf1 * 2);
    ushort_t* wf1l = (ushort_t*)base;             base += alignup(wf1 * 2);
    ushort_t* wf2h = (ushort_t*)base;             base += alignup(wf2 * 2);
    ushort_t* wf2l = (ushort_t*)base;             base += alignup(wf2 * 2);
    size_t fixed = (size_t)(base - (char*)d_ws);

    // per-chunk: X bf16, X2 bf16, xr0 f32, accs i64 (w0a1|za1|w0a2|za2|pacc), row0v f32
    auto need = [&](int bcx) -> size_t {
        size_t rn = (size_t)bcx * NN;
        return fixed
             + alignup(rn * 128 * 2)             // X bf16
             + alignup(rn * 96 * 2)              // X2 bf16
             + alignup((size_t)bcx * 96 * 4)     // xr0
             + alignup((size_t)bcx * 392 * 8)    // i64 accumulators
             + alignup((size_t)bcx * 96 * 4);    // row0v
    };
    int bc = BB;
    while (bc > 1 && need(bc) > ws_size) bc >>= 1;

    k_wprep<128><<<6, 256, 0, stream>>>(Wl1, wf1h, wf1l);
    k_wprep<96><<<5, 256, 0, stream>>>(Wl2, wf2h, wf2l);

    for (int cb = 0; cb < BB; cb += bc) {
        size_t rn = (size_t)bc * NN;
        char* p = base;
        ushort_t* Xbuf  = (ushort_t*)p; p += alignup(rn * 128 * 2);
        ushort_t* X2buf = (ushort_t*)p; p += alignup(rn * 96 * 2);
        float*    xr0b  = (float*)p;    p += alignup((size_t)bc * 96 * 4);
        ull_t*    accs  = (ull_t*)p;    p += alignup((size_t)bc * 392 * 8);
        float*    row0v = (float*)p;
        ull_t* w0a1 = accs;
        ull_t* za1  = w0a1 + (size_t)bc * 96;
        ull_t* w0a2 = za1 + (size_t)bc * 4;
        ull_t* za2  = w0a2 + (size_t)bc * 96;
        ull_t* pacc = za2 + (size_t)bc * 4;

        const float* inC = in0 + (size_t)cb * NN * FIN;
        float* outC = (float*)d_out + (size_t)cb * 256;
        int nz = bc * 392;

        k_zero64<<<(nz + 255) / 256, 256, 0, stream>>>(accs, nz);
        k_fcnode<<<bc * NN / 64, 256, 0, stream>>>(inC, W_node, b_node, lnn_g, lnn_b, Xbuf);

        // conv1 (stores Xout, fused attention accumulation)
        k_xr0<128><<<bc, 128, 0, stream>>>(Xbuf, Wr1, br1, xr0b);
        k_conv<128, false><<<bc * NN / 128, 256, 0, stream>>>(
            Xbuf, wf1h, wf1l, bl1, att1, xr0b, bias1, lnc1_g, lnc1_b,
            w0a1, za1, X2buf, nullptr, nullptr);
        k_row0<1><<<bc, 128, 0, stream>>>(w0a1, za1, bias1, lnc1_g, lnc1_b,
                                          X2buf, nullptr);

        // conv2 (no Xout store; fused attention + pooling accumulation)
        k_xr0<96><<<bc, 128, 0, stream>>>(X2buf, Wr2, br2, xr0b);
        k_conv<96, true><<<bc * NN / 128, 256, 0, stream>>>(
            X2buf, wf2h, wf2l, bl2, att2, xr0b, bias2, lnc2_g, lnc2_b,
            w0a2, za2, nullptr, pacc, tptr);
        k_row0<2><<<bc, 128, 0, stream>>>(w0a2, za2, bias2, lnc2_g, lnc2_b,
                                          nullptr, row0v);

        // output head (pool finalize + row-0 term fused)
        k_out<<<bc, 256, 0, stream>>>(pacc, row0v, tptr, W_out, b_out,
                                      lno_g, lno_b, outC);
    }
}

// Round 7
// 236.266 us; speedup vs baseline: 3.2017x; 1.0110x over previous
//
#include <hip/hip_runtime.h>
#include <hip/hip_bf16.h>
#include <math.h>

#define BB 128
#define NN 2048
#define FIN 17

#define SCALE_I 1048576.0f          // 2^20 fixed-point scale
#define INV_SCALE 9.5367431640625e-07f

typedef unsigned short ushort_t;
typedef unsigned long long ull_t;
typedef __attribute__((ext_vector_type(4))) unsigned short u16x4;
typedef __attribute__((ext_vector_type(8))) short s16x8;
typedef __attribute__((ext_vector_type(4))) float f32x4;

__device__ __forceinline__ float b2f(unsigned short u) {
    unsigned int v = ((unsigned int)u) << 16;
    return __builtin_bit_cast(float, v);
}
__device__ __forceinline__ unsigned short f2b(float f) {
    __hip_bfloat16 h = __float2bfloat16(f);
    return __builtin_bit_cast(unsigned short, h);
}
// fast RNE f32->bf16 for finite values (no NaN path)
__device__ __forceinline__ unsigned short f2b_fast(float f) {
    unsigned int u = __builtin_bit_cast(unsigned int, f);
    u += 0x7FFFu + ((u >> 16) & 1u);
    return (unsigned short)(u >> 16);
}
// gelu via A&S 7.1.26 erf approx (|abs err| <= 1.5e-7)
__device__ __forceinline__ float gelu_f(float x) {
    float ax = fabsf(x) * 0.70710678118654752f;
    float t = 1.0f / (1.0f + 0.3275911f * ax);
    float poly = t * (0.254829592f +
                 t * (-0.284496736f +
                 t * (1.421413741f +
                 t * (-1.453152027f +
                 t * 1.061405429f))));
    float erfv = 1.0f - poly * __expf(-ax * ax);
    erfv = (x >= 0.f) ? erfv : -erfv;
    return 0.5f * x * (1.0f + erfv);
}
__device__ __forceinline__ float lrelu_f(float x) {
    return x >= 0.0f ? x : 0.2f * x;
}
__device__ __forceinline__ ull_t q20(float x) {
    return (ull_t)(long long)(x * SCALE_I);
}

// ---------------- zero integer accumulators
__global__ __launch_bounds__(256) void k_zero64(ull_t* __restrict__ p, int n) {
    int i = blockIdx.x * 256 + threadIdx.x;
    if (i < n) p[i] = 0ull;
}

// ---------------- Stage 1: x = LN(gelu(in @ W_node + b_node)) -> [Bc*N,128] bf16
__global__ __launch_bounds__(256) void k_fcnode(
    const float* __restrict__ X, const float* __restrict__ W,
    const float* __restrict__ bias, const float* __restrict__ g,
    const float* __restrict__ beta, ushort_t* __restrict__ out) {
    __shared__ float Ws[FIN * 128];
    __shared__ float xs[64 * FIN];
    __shared__ float bl[128], gl[128], bet[128];
    int tid = threadIdx.x;
    long long rbase = (long long)blockIdx.x * 64;
    for (int i = tid; i < FIN * 128; i += 256) Ws[i] = W[i];
    for (int i = tid; i < 64 * FIN; i += 256) xs[i] = X[rbase * FIN + i];
    if (tid < 128) {
        bl[tid] = bias[tid]; gl[tid] = g[tid]; bet[tid] = beta[tid];
    }
    __syncthreads();
    int lane32 = tid & 31, sub = tid >> 5;
    int c0 = 4 * lane32;
    f32x4 acc[8] = {};
#pragma unroll
    for (int k = 0; k < FIN; k++) {
        f32x4 w = *(const f32x4*)(Ws + k * 128 + c0);
#pragma unroll
        for (int r = 0; r < 8; r++) {
            float xv = xs[(sub + 8 * r) * FIN + k];
            acc[r][0] = fmaf(xv, w[0], acc[r][0]);
            acc[r][1] = fmaf(xv, w[1], acc[r][1]);
            acc[r][2] = fmaf(xv, w[2], acc[r][2]);
            acc[r][3] = fmaf(xv, w[3], acc[r][3]);
        }
    }
#pragma unroll
    for (int r = 0; r < 8; r++) {
        int lr = sub + 8 * r;
        float v[4], s = 0.f, sq = 0.f;
#pragma unroll
        for (int j = 0; j < 4; j++) {
            v[j] = gelu_f(acc[r][j] + bl[c0 + j]);
            s += v[j]; sq += v[j] * v[j];
        }
#pragma unroll
        for (int mk = 16; mk >= 1; mk >>= 1) {
            s += __shfl_xor(s, mk, 32); sq += __shfl_xor(sq, mk, 32);
        }
        float mean = s * (1.f / 128.f);
        float var = sq * (1.f / 128.f) - mean * mean;
        float rstd = rsqrtf(var + 1e-5f);
        u16x4 o4;
#pragma unroll
        for (int j = 0; j < 4; j++)
            o4[j] = f2b_fast((v[j] - mean) * rstd * gl[c0 + j] + bet[c0 + j]);
        *(u16x4*)(out + (rbase + lr) * 128 + c0) = o4;
    }
}

// ---------------- W fragment prep: f32 [K,96] -> bf16 hi/lo in MFMA B-lane layout
template <int K>
__global__ __launch_bounds__(256) void k_wprep(
    const float* __restrict__ W, ushort_t* __restrict__ hi, ushort_t* __restrict__ lo) {
    constexpr int S = K / 32;
    int gid = blockIdx.x * 256 + threadIdx.x;
    if (gid >= 6 * S * 64) return;
    int lane = gid & 63, f = gid >> 6;
    int t = f / S, s = f - t * S;
    int n = 16 * t + (lane & 15);
    int kbase = 32 * s + 8 * (lane >> 4);
#pragma unroll
    for (int j = 0; j < 8; j++) {
        float w = W[(kbase + j) * 96 + n];
        ushort_t h = f2b(w);
        float rem = w - b2f(h);
        hi[gid * 8 + j] = h;
        lo[gid * 8 + j] = f2b(rem);
    }
}

// ---------------- xr0[b] = X[b,0,:] @ Wr + br  -> [Bc,96] f32
template <int K>
__global__ __launch_bounds__(128) void k_xr0(
    const ushort_t* __restrict__ X, const float* __restrict__ Wr,
    const float* __restrict__ br, float* __restrict__ xr0) {
    int b = blockIdx.x, c = threadIdx.x;
    __shared__ float xs[K];
    if (threadIdx.x < K) xs[threadIdx.x] = b2f(X[(long long)b * NN * K + threadIdx.x]);
    __syncthreads();
    if (c >= 96) return;
    float acc = br[c];
    for (int k = 0; k < K; k++) acc = fmaf(xs[k], Wr[k * 96 + c], acc);
    xr0[b * 96 + c] = acc;
}

// ---------------- MFMA conv with fused attention (+pool) accumulation.
// Block = 256 thr = 4 waves; wave: 32 rows x 96 cols. DETERMINISTIC via
// integer fixed-point atomics. W-fragments staged once per block in LDS
// (all 4 waves read identical fragments).
template <int K, bool POOLF>
__global__ __launch_bounds__(256) void k_conv(
    const ushort_t* __restrict__ X,     // [Bc*N,K] bf16
    const ushort_t* __restrict__ Whi, const ushort_t* __restrict__ Wlo,
    const float* __restrict__ bl, const float* __restrict__ att,
    const float* __restrict__ xr0,      // [Bc,96]
    const float* __restrict__ bias, const float* __restrict__ lng,
    const float* __restrict__ lnb,
    ull_t* __restrict__ w0acc,          // [Bc*96]  fixed-point sum e*xl
    ull_t* __restrict__ zacc,           // [Bc*4]   fixed-point sum e per head
    ushort_t* __restrict__ Xout,        // layer1: [Bc*N,96] bf16
    ull_t* __restrict__ pacc,           // layer2: [Bc*192] (ps | pw) fixed-point
    const float* __restrict__ tptr)
{
    constexpr int S = K / 32;
    constexpr int NFRAG = 6 * S * 64;
    __shared__ s16x8 lWh[NFRAG];
    __shared__ s16x8 lWl[NFRAG];
    int tid = threadIdx.x;
    {
        const s16x8* gh = (const s16x8*)Whi;
        const s16x8* gl8 = (const s16x8*)Wlo;
        for (int i = tid; i < NFRAG; i += 256) {
            lWh[i] = gh[i];
            lWl[i] = gl8[i];
        }
    }
    __syncthreads();

    int wave = tid >> 6, lane = tid & 63;
    int hi4 = lane >> 4, cl = lane & 15;
    int row0 = blockIdx.x * 128 + wave * 32;
    int b = row0 >> 11;

    f32x4 acc[2][6] = {};
#pragma unroll
    for (int s = 0; s < S; s++) {
        s16x8 a0 = *(const s16x8*)(X + (size_t)(row0 + cl) * K + s * 32 + hi4 * 8);
        s16x8 a1 = *(const s16x8*)(X + (size_t)(row0 + 16 + cl) * K + s * 32 + hi4 * 8);
#pragma unroll
        for (int t = 0; t < 6; t++) {
            s16x8 bh = lWh[(t * S + s) * 64 + lane];
            s16x8 bo = lWl[(t * S + s) * 64 + lane];
            acc[0][t] = __builtin_amdgcn_mfma_f32_16x16x32_bf16(a0, bh, acc[0][t], 0, 0, 0);
            acc[0][t] = __builtin_amdgcn_mfma_f32_16x16x32_bf16(a0, bo, acc[0][t], 0, 0, 0);
            acc[1][t] = __builtin_amdgcn_mfma_f32_16x16x32_bf16(a1, bh, acc[1][t], 0, 0, 0);
            acc[1][t] = __builtin_amdgcn_mfma_f32_16x16x32_bf16(a1, bo, acc[1][t], 0, 0, 0);
        }
    }

    float blc[6], xrc[6], attc[6], bic[6], gc[6], bcc[6];
#pragma unroll
    for (int t = 0; t < 6; t++) {
        int c = 16 * t + cl;
        blc[t] = bl[c]; xrc[t] = xr0[b * 96 + c]; attc[t] = att[c];
        bic[t] = bias[c]; gc[t] = lng[c]; bcc[t] = lnb[c];
    }
    float tv = POOLF ? tptr[0] : 0.f;

    float w0p[6] = {0.f, 0.f, 0.f, 0.f, 0.f, 0.f};
    float zp[3] = {0.f, 0.f, 0.f};
    float psp[6] = {0.f, 0.f, 0.f, 0.f, 0.f, 0.f};
    float pwp[6] = {0.f, 0.f, 0.f, 0.f, 0.f, 0.f};

#pragma unroll
    for (int q = 0; q < 2; q++) {
#pragma unroll
        for (int i = 0; i < 4; i++) {
            int row = row0 + q * 16 + hi4 * 4 + i;
            float xl[6];
#pragma unroll
            for (int t = 0; t < 6; t++) xl[t] = acc[q][t][i] + blc[t];
            // score partials per head (pre-reduction)
            float pv[6];
#pragma unroll
            for (int t = 0; t < 6; t++) pv[t] = attc[t] * lrelu_f(xl[t] + xrc[t]);
            float p0 = pv[0] + pv[1], p1 = pv[2] + pv[3], p2 = pv[4] + pv[5];
            // output-path gelu partials (independent of scores)
            float o[6], s = 0.f, sq = 0.f;
#pragma unroll
            for (int t = 0; t < 6; t++) {
                o[t] = gelu_f(xl[t] + bic[t]);
                s += o[t]; sq += o[t] * o[t];
            }
            // single combined 4-step tree over the 16-lane cl group
#pragma unroll
            for (int mk = 1; mk <= 8; mk <<= 1) {
                p0 += __shfl_xor(p0, mk, 64);
                p1 += __shfl_xor(p1, mk, 64);
                p2 += __shfl_xor(p2, mk, 64);
                s  += __shfl_xor(s,  mk, 64);
                sq += __shfl_xor(sq, mk, 64);
            }
            float e0 = __expf(fminf(p0, 24.f));
            float e1 = __expf(fminf(p1, 24.f));
            float e2 = __expf(fminf(p2, 24.f));
            w0p[0] = fmaf(e0, xl[0], w0p[0]); w0p[1] = fmaf(e0, xl[1], w0p[1]);
            w0p[2] = fmaf(e1, xl[2], w0p[2]); w0p[3] = fmaf(e1, xl[3], w0p[3]);
            w0p[4] = fmaf(e2, xl[4], w0p[4]); w0p[5] = fmaf(e2, xl[5], w0p[5]);
            zp[0] += e0; zp[1] += e1; zp[2] += e2;
            float mean = s * (1.f / 96.f);
            float var = sq * (1.f / 96.f) - mean * mean;
            float rstd = rsqrtf(var + 1e-5f);
            if ((row & (NN - 1)) != 0) {
                if (!POOLF) {
#pragma unroll
                    for (int t = 0; t < 6; t++)
                        Xout[(size_t)row * 96 + 16 * t + cl] =
                            f2b_fast((o[t] - mean) * rstd * gc[t] + bcc[t]);
                } else {
#pragma unroll
                    for (int t = 0; t < 6; t++) {
                        float v = (o[t] - mean) * rstd * gc[t] + bcc[t];
                        float pe = __expf(fminf(tv * v, 24.f));
                        psp[t] += pe;
                        pwp[t] = fmaf(pe, v, pwp[t]);
                    }
                }
            }
        }
    }

    // reduce across the 4 hi4 groups (lanes cl, cl+16, cl+32, cl+48)
#pragma unroll
    for (int t = 0; t < 6; t++) {
        w0p[t] += __shfl_xor(w0p[t], 16, 64);
        w0p[t] += __shfl_xor(w0p[t], 32, 64);
    }
#pragma unroll
    for (int h = 0; h < 3; h++) {
        zp[h] += __shfl_xor(zp[h], 16, 64);
        zp[h] += __shfl_xor(zp[h], 32, 64);
    }
    if (POOLF) {
#pragma unroll
        for (int t = 0; t < 6; t++) {
            psp[t] += __shfl_xor(psp[t], 16, 64);
            psp[t] += __shfl_xor(psp[t], 32, 64);
            pwp[t] += __shfl_xor(pwp[t], 16, 64);
            pwp[t] += __shfl_xor(pwp[t], 32, 64);
        }
    }
    if (lane < 16) {
#pragma unroll
        for (int t = 0; t < 6; t++)
            atomicAdd(w0acc + b * 96 + 16 * t + lane, q20(w0p[t]));
        if (POOLF) {
#pragma unroll
            for (int t = 0; t < 6; t++) {
                atomicAdd(pacc + b * 192 + 16 * t + lane, q20(psp[t]));
                atomicAdd(pacc + b * 192 + 96 + 16 * t + lane, q20(pwp[t]));
            }
        }
    }
    if (lane == 0) {
        atomicAdd(zacc + b * 4 + 0, q20(zp[0]));
        atomicAdd(zacc + b * 4 + 1, q20(zp[1]));
        atomicAdd(zacc + b * 4 + 2, q20(zp[2]));
    }
}

// ---------------- finalize node-0 row: x0 = LN(gelu(w0acc/z + bias))
// LAYER 1: write X2 row 0 (bf16).  LAYER 2: write row-0 LN value to row0v.
template <int LAYER>
__global__ __launch_bounds__(128) void k_row0(
    const ull_t* __restrict__ w0acc, const ull_t* __restrict__ zacc,
    const float* __restrict__ bias, const float* __restrict__ g,
    const float* __restrict__ beta, ushort_t* __restrict__ X2,
    float* __restrict__ row0v) {
    int b = blockIdx.x, t = threadIdx.x;
    __shared__ float vv[96];
    __shared__ float red2[2];
    float val = 0.f;
    if (t < 96) {
        float wf = (float)(long long)w0acc[b * 96 + t];
        float zf = (float)(long long)zacc[b * 4 + (t >> 5)];
        float out0 = wf / zf;   // fixed-point scale cancels
        val = gelu_f(out0 + bias[t]);
        vv[t] = val;
    }
    __syncthreads();
    if (t < 32) {
        float a = vv[t], b2 = vv[t + 32], c = vv[t + 64];
        float s = a + b2 + c, sq = a * a + b2 * b2 + c * c;
#pragma unroll
        for (int mk = 16; mk >= 1; mk >>= 1) { s += __shfl_xor(s, mk, 32); sq += __shfl_xor(sq, mk, 32); }
        if (t == 0) { red2[0] = s; red2[1] = sq; }
    }
    __syncthreads();
    float mean = red2[0] * (1.f / 96.f);
    float var = red2[1] * (1.f / 96.f) - mean * mean;
    float rstd = rsqrtf(var + 1e-5f);
    if (t < 96) {
        float ln = (val - mean) * rstd * g[t] + beta[t];
        if (LAYER == 1) {
            X2[(long long)b * NN * 96 + t] = f2b(ln);
        } else {
            row0v[b * 96 + t] = ln;
        }
    }
}

// ---------------- final: pooled = (pw + row0 term)/(ps + row0 term);
// out = LN(gelu(pooled @ W_out + b_out)) -> [Bc,256]
__global__ __launch_bounds__(256) void k_out(
    const ull_t* __restrict__ pacc, const float* __restrict__ row0v,
    const float* __restrict__ tptr, const float* __restrict__ W,
    const float* __restrict__ bias, const float* __restrict__ g,
    const float* __restrict__ beta, float* __restrict__ out) {
    int b = blockIdx.x, c = threadIdx.x;
    __shared__ float ps[96];
    __shared__ float rs[4], rq[4];
    if (c < 96) {
        float ln0 = row0v[b * 96 + c];
        float pe0 = __expf(fminf(tptr[0] * ln0, 24.f));
        float S = (float)(long long)pacc[b * 192 + c] * INV_SCALE + pe0;
        float Wp = (float)(long long)pacc[b * 192 + 96 + c] * INV_SCALE + pe0 * ln0;
        ps[c] = Wp / S;
    }
    __syncthreads();
    float acc = bias[c];
    for (int k = 0; k < 96; k++) acc = fmaf(ps[k], W[k * 256 + c], acc);
    float v = gelu_f(acc);
    float s = v, sq = v * v;
#pragma unroll
    for (int mk = 32; mk >= 1; mk >>= 1) { s += __shfl_xor(s, mk, 64); sq += __shfl_xor(sq, mk, 64); }
    if ((c & 63) == 0) { rs[c >> 6] = s; rq[c >> 6] = sq; }
    __syncthreads();
    s = rs[0] + rs[1] + rs[2] + rs[3];
    sq = rq[0] + rq[1] + rq[2] + rq[3];
    float mean = s * (1.f / 256.f);
    float var = sq * (1.f / 256.f) - mean * mean;
    float rstd = rsqrtf(var + 1e-5f);
    out[b * 256 + c] = (v - mean) * rstd * g[c] + beta[c];
}

extern "C" void kernel_launch(void* const* d_in, const int* in_sizes, int n_in,
                              void* d_out, int out_size, void* d_ws, size_t ws_size,
                              hipStream_t stream) {
    const float* in0    = (const float*)d_in[0];
    const float* W_node = (const float*)d_in[1];
    const float* b_node = (const float*)d_in[2];
    const float* lnn_g  = (const float*)d_in[3];
    const float* lnn_b  = (const float*)d_in[4];
    const float* Wl1 = (const float*)d_in[5];
    const float* bl1 = (const float*)d_in[6];
    const float* Wr1 = (const float*)d_in[7];
    const float* br1 = (const float*)d_in[8];
    const float* att1 = (const float*)d_in[9];
    const float* bias1 = (const float*)d_in[10];
    const float* lnc1_g = (const float*)d_in[11];
    const float* lnc1_b = (const float*)d_in[12];
    const float* Wl2 = (const float*)d_in[13];
    const float* bl2 = (const float*)d_in[14];
    const float* Wr2 = (const float*)d_in[15];
    const float* br2 = (const float*)d_in[16];
    const float* att2 = (const float*)d_in[17];
    const float* bias2 = (const float*)d_in[18];
    const float* lnc2_g = (const float*)d_in[19];
    const float* lnc2_b = (const float*)d_in[20];
    const float* tptr = (const float*)d_in[21];
    const float* W_out = (const float*)d_in[22];
    const float* b_out = (const float*)d_in[23];
    const float* lno_g = (const float*)d_in[24];
    const float* lno_b = (const float*)d_in[25];

    auto alignup = [](size_t x) { return (x + 255) & ~(size_t)255; };

    // fixed region: MFMA B-fragments (hi/lo) for both conv layers
    const size_t wf1 = (size_t)6 * 4 * 64 * 8;  // K=128
    const size_t wf2 = (size_t)6 * 3 * 64 * 8;  // K=96
    char* base = (char*)d_ws;
    ushort_t* wf1h = (ushort_t*)base;             base += alignup(wf1 * 2);
    ushort_t* wf1l = (ushort_t*)base;             base += alignup(wf1 * 2);
    ushort_t* wf2h = (ushort_t*)base;             base += alignup(wf2 * 2);
    ushort_t* wf2l = (ushort_t*)base;             base += alignup(wf2 * 2);
    size_t fixed = (size_t)(base - (char*)d_ws);

    // per-chunk: X bf16, X2 bf16, xr0 f32, accs i64 (w0a1|za1|w0a2|za2|pacc), row0v f32
    auto need = [&](int bcx) -> size_t {
        size_t rn = (size_t)bcx * NN;
        return fixed
             + alignup(rn * 128 * 2)             // X bf16
             + alignup(rn * 96 * 2)              // X2 bf16
             + alignup((size_t)bcx * 96 * 4)     // xr0
             + alignup((size_t)bcx * 392 * 8)    // i64 accumulators
             + alignup((size_t)bcx * 96 * 4);    // row0v
    };
    int bc = BB;
    while (bc > 1 && need(bc) > ws_size) bc >>= 1;

    k_wprep<128><<<6, 256, 0, stream>>>(Wl1, wf1h, wf1l);
    k_wprep<96><<<5, 256, 0, stream>>>(Wl2, wf2h, wf2l);

    for (int cb = 0; cb < BB; cb += bc) {
        size_t rn = (size_t)bc * NN;
        char* p = base;
        ushort_t* Xbuf  = (ushort_t*)p; p += alignup(rn * 128 * 2);
        ushort_t* X2buf = (ushort_t*)p; p += alignup(rn * 96 * 2);
        float*    xr0b  = (float*)p;    p += alignup((size_t)bc * 96 * 4);
        ull_t*    accs  = (ull_t*)p;    p += alignup((size_t)bc * 392 * 8);
        float*    row0v = (float*)p;
        ull_t* w0a1 = accs;
        ull_t* za1  = w0a1 + (size_t)bc * 96;
        ull_t* w0a2 = za1 + (size_t)bc * 4;
        ull_t* za2  = w0a2 + (size_t)bc * 96;
        ull_t* pacc = za2 + (size_t)bc * 4;

        const float* inC = in0 + (size_t)cb * NN * FIN;
        float* outC = (float*)d_out + (size_t)cb * 256;
        int nz = bc * 392;

        k_zero64<<<(nz + 255) / 256, 256, 0, stream>>>(accs, nz);
        k_fcnode<<<bc * NN / 64, 256, 0, stream>>>(inC, W_node, b_node, lnn_g, lnn_b, Xbuf);

        // conv1 (stores Xout, fused attention accumulation)
        k_xr0<128><<<bc, 128, 0, stream>>>(Xbuf, Wr1, br1, xr0b);
        k_conv<128, false><<<bc * NN / 128, 256, 0, stream>>>(
            Xbuf, wf1h, wf1l, bl1, att1, xr0b, bias1, lnc1_g, lnc1_b,
            w0a1, za1, X2buf, nullptr, nullptr);
        k_row0<1><<<bc, 128, 0, stream>>>(w0a1, za1, bias1, lnc1_g, lnc1_b,
                                          X2buf, nullptr);

        // conv2 (no Xout store; fused attention + pooling accumulation)
        k_xr0<96><<<bc, 128, 0, stream>>>(X2buf, Wr2, br2, xr0b);
        k_conv<96, true><<<bc * NN / 128, 256, 0, stream>>>(
            X2buf, wf2h, wf2l, bl2, att2, xr0b, bias2, lnc2_g, lnc2_b,
            w0a2, za2, nullptr, pacc, tptr);
        k_row0<2><<<bc, 128, 0, stream>>>(w0a2, za2, bias2, lnc2_g, lnc2_b,
                                          nullptr, row0v);

        // output head (pool finalize + row-0 term fused)
        k_out<<<bc, 256, 0, stream>>>(pacc, row0v, tptr, W_out, b_out,
                                      lno_g, lno_b, outC);
    }
}